// Round 11
// baseline (135.674 us; speedup 1.0000x reference)
//
#include <hip/hip_runtime.h>
#include <hip/hip_fp16.h>
#include <cstdint>
#include <cstddef>
#include <type_traits>

// GCN refold: H'_l = dinv * (X_l @ W_l)  (fp16), layer out = relu(dinv*(sum+self)+b)
// GEMM via MFMA bf16 hi/lo split. CSR build: prep(wfrag+hist-partials) ->
// bscan(sum+scan) -> bin(int4 nt loads, block-local scatter) -> fill2 (LDS-local).
// Non-temporal hints on single-use streams to keep Hh resident in XCD L2s.
// Requires N < 65536.

constexpr int DIM = 128;
#define BSH 6                 // 64 nodes per bucket
#define HB 128                // hist blocks (also wfrag: 128*256 = 32768 threads)
#define BIN_EPT 16            // edges per thread in k_bin (multiple of 4)
#define FT 8                  // src tiles (in-row CSR order; harmless)
#define FSH 13
#define STAGE 2048            // LDS edge stage per bucket

typedef __attribute__((ext_vector_type(8))) short bf16x8;   // 8 bf16 (4 VGPRs)
typedef __attribute__((ext_vector_type(4))) float f32x4;
typedef __attribute__((ext_vector_type(4))) int   i32x4;

__device__ __forceinline__ short bf16h(float x) {
    unsigned u = __float_as_uint(x);
    return (short)((u + 0x7FFFu + ((u >> 16) & 1u)) >> 16);  // RNE bf16
}
__device__ __forceinline__ float bf16f(short h) {
    return __uint_as_float(((unsigned)(unsigned short)h) << 16);
}
__device__ __forceinline__ i32x4 nt_load4(const int* p) {
    return __builtin_nontemporal_load((const i32x4*)p);
}
__device__ __forceinline__ f32x4 nt_load4f(const float* p) {
    return __builtin_nontemporal_load((const f32x4*)p);
}

// ---- prep: W->bf16 hi/lo frags (both layers) + hist partials (no atomics) --
__global__ __launch_bounds__(256) void k_prep(const float* __restrict__ W1,
                                              const float* __restrict__ W2,
                                              short* __restrict__ Bh1,
                                              short* __restrict__ Bl1,
                                              short* __restrict__ Bh2,
                                              short* __restrict__ Bl2,
                                              const int* __restrict__ dst,
                                              int* __restrict__ h_part,
                                              int E, int nb) {
    // part 1: weight fragments (exactly HB*256 = 32768 threads, 2 layers)
    {
        int idx = blockIdx.x * 256 + threadIdx.x;
        const float* W = (idx < 16384) ? W1 : W2;
        short* Bh = (idx < 16384) ? Bh1 : Bh2;
        short* Bl = (idx < 16384) ? Bl1 : Bl2;
        int id = idx & 16383;
        int j  = id & 7;
        int l  = (id >> 3) & 63;
        int ks = (id >> 9) & 3;
        int nt = id >> 11;
        int k  = ks * 32 + ((l >> 4) * 8) + j;
        int c  = nt * 16 + (l & 15);
        float w = W[k * 128 + c];
        short h = bf16h(w);
        Bh[id] = h;
        Bl[id] = bf16h(w - bf16f(h));
    }
    // part 2: bucket histogram partials (LDS, written per block — no atomics)
    __shared__ int h[1024];
    for (int i = threadIdx.x; i < 1024; i += 256) h[i] = 0;
    __syncthreads();
    int E4 = E >> 2;
    for (int v = blockIdx.x * 256 + threadIdx.x; v < E4; v += HB * 256) {
        i32x4 d4 = nt_load4(dst + v * 4);
        atomicAdd(&h[d4.x >> BSH], 1);
        atomicAdd(&h[d4.y >> BSH], 1);
        atomicAdd(&h[d4.z >> BSH], 1);
        atomicAdd(&h[d4.w >> BSH], 1);
    }
    if (blockIdx.x == 0 && threadIdx.x < (E & 3))
        atomicAdd(&h[dst[E4 * 4 + threadIdx.x] >> BSH], 1);
    __syncthreads();
    for (int i = threadIdx.x; i < nb; i += 256)
        h_part[blockIdx.x * 1024 + i] = h[i];
}

// ---- bucket scan: sum HB partials per bucket, exclusive scan ------------
__global__ __launch_bounds__(1024) void k_bscan(const int* __restrict__ h_part,
                                                int* __restrict__ bptr,
                                                int* __restrict__ bcur, int nb, int E) {
    __shared__ int s[1024];
    int t = threadIdx.x;
    int v = 0;
    if (t < nb)
        for (int b = 0; b < HB; b++) v += h_part[b * 1024 + t];
    s[t] = v;
    __syncthreads();
    for (int off = 1; off < 1024; off <<= 1) {
        int u = (t >= off) ? s[t - off] : 0;
        __syncthreads();
        s[t] += u;
        __syncthreads();
    }
    if (t < nb) { int ex = s[t] - v; bptr[t] = ex; bcur[t] = ex; }
    if (t == 0) bptr[nb] = E;
}

// ---- bin edges into bucket runs (block-level reservation, int4 nt loads) --
__global__ __launch_bounds__(256) void k_bin(const int* __restrict__ src,
                                             const int* __restrict__ dst,
                                             int* __restrict__ bcur,
                                             unsigned* __restrict__ pairs,
                                             int E, int nb) {
    __shared__ int h[1024];     // local counts
    __shared__ int base[1024];  // reserved cursors
    for (int i = threadIdx.x; i < nb; i += 256) h[i] = 0;
    __syncthreads();

    int e0 = blockIdx.x * 256 * BIN_EPT;
    unsigned u[BIN_EPT];
    int cnt = 0;
#pragma unroll
    for (int j = 0; j < BIN_EPT / 4; j++) {
        int b4 = e0 + j * 1024 + threadIdx.x * 4;
        if (b4 + 4 <= E) {
            i32x4 s4 = nt_load4(src + b4);
            i32x4 d4 = nt_load4(dst + b4);
            u[4 * j + 0] = ((unsigned)d4.x << 16) | (unsigned)s4.x;
            u[4 * j + 1] = ((unsigned)d4.y << 16) | (unsigned)s4.y;
            u[4 * j + 2] = ((unsigned)d4.z << 16) | (unsigned)s4.z;
            u[4 * j + 3] = ((unsigned)d4.w << 16) | (unsigned)s4.w;
            atomicAdd(&h[d4.x >> BSH], 1);
            atomicAdd(&h[d4.y >> BSH], 1);
            atomicAdd(&h[d4.z >> BSH], 1);
            atomicAdd(&h[d4.w >> BSH], 1);
            cnt = 4 * j + 4;
        } else {
#pragma unroll
            for (int k = 0; k < 4; k++) {
                int e = b4 + k;
                if (e < E) {
                    int d = dst[e];
                    u[4 * j + k] = ((unsigned)d << 16) | (unsigned)src[e];
                    atomicAdd(&h[d >> BSH], 1);
                    cnt = 4 * j + k + 1;
                }
            }
        }
    }
    __syncthreads();
    for (int i = threadIdx.x; i < nb; i += 256) {
        int c = h[i];
        base[i] = c ? atomicAdd(&bcur[i], c) : 0;
    }
    __syncthreads();
#pragma unroll
    for (int j = 0; j < BIN_EPT; j++) {
        if (j < cnt) {
            int pos = atomicAdd(&base[u[j] >> 22], 1);
            pairs[pos] = u[j];
        }
    }
}

// ---- per-bucket: row_ptr, dinv, CSR col fill in src-tile order ----------
__global__ __launch_bounds__(256) void k_fill2(const unsigned* __restrict__ pairs,
                                               const int* __restrict__ bptr,
                                               int* __restrict__ row_ptr,
                                               float* __restrict__ dinv,
                                               int* __restrict__ col,
                                               int N, int nb, int E) {
    __shared__ unsigned sp[STAGE];
    __shared__ int lcnt[64 * FT];   // counts, then running cursors
    int b = blockIdx.x;
    int node0 = b << BSH;
    int beg = bptr[b], end = bptr[b + 1];
    int cnt = end - beg;
    bool useStage = (cnt <= STAGE);

    for (int i = threadIdx.x; i < 64 * FT; i += 256) lcnt[i] = 0;
    __syncthreads();

    // pass A: (stage +) count per (node, src-tile)
    for (int i = threadIdx.x; i < cnt; i += 256) {
        unsigned u = __builtin_nontemporal_load(pairs + beg + i);
        if (useStage) sp[i] = u;
        atomicAdd(&lcnt[((u >> 16) & 63) * FT + ((u & 0xffffu) >> FSH)], 1);
    }
    __syncthreads();

    // wave 0: per-node totals, wave-scan, write row_ptr/dinv, tile cursors
    if (threadIdx.x < 64) {
        int t = threadIdx.x;
        int c[FT]; int sum = 0;
#pragma unroll
        for (int f = 0; f < FT; f++) { c[f] = lcnt[t * FT + f]; sum += c[f]; }
        int x = sum;
#pragma unroll
        for (int off = 1; off < 64; off <<= 1) {
            int y = __shfl_up(x, off, 64);
            if (t >= off) x += y;
        }
        int nodebase = beg + x - sum;   // exclusive in-bucket prefix
        int node = node0 + t;
        if (node < N) {
            row_ptr[node] = nodebase;
            dinv[node] = rsqrtf((float)sum + 1.0f);
        }
        int run = nodebase;
#pragma unroll
        for (int f = 0; f < FT; f++) { lcnt[t * FT + f] = run; run += c[f]; }
        if (b == nb - 1 && t == 0) row_ptr[N] = E;
    }
    __syncthreads();

    // pass B: place
    for (int i = threadIdx.x; i < cnt; i += 256) {
        unsigned u = useStage ? sp[i] : pairs[beg + i];
        unsigned s = u & 0xffffu;
        int pos = atomicAdd(&lcnt[((u >> 16) & 63) * FT + (s >> FSH)], 1);
        col[pos] = (int)s;
    }
}

// ---------------- MFMA GEMM: H' = dinv * (X @ W), fp16 out --------------
__device__ __forceinline__ void load8(const float* p, float* v, bool nt) {
    f32x4 a = nt ? nt_load4f(p) : *(const f32x4*)p;
    f32x4 b = nt ? nt_load4f(p + 4) : *(const f32x4*)(p + 4);
    v[0] = a.x; v[1] = a.y; v[2] = a.z; v[3] = a.w;
    v[4] = b.x; v[5] = b.y; v[6] = b.z; v[7] = b.w;
}
__device__ __forceinline__ void load8(const __half* p, float* v, bool) {
    f32x4 a = *(const f32x4*)p;   // 8 halves
    const __half2* h = (const __half2*)&a;
#pragma unroll
    for (int i = 0; i < 4; i++) {
        float2 f = __half22float2(h[i]);
        v[2 * i] = f.x; v[2 * i + 1] = f.y;
    }
}

template <typename T>
__global__ __launch_bounds__(256) void k_mm(const T* __restrict__ X,
                                            const short* __restrict__ Bhp,
                                            const short* __restrict__ Blp,
                                            const float* __restrict__ dinv,
                                            __half* __restrict__ Hh, int N) {
    int gw   = (blockIdx.x * 256 + threadIdx.x) >> 6;
    int lane = threadIdx.x & 63;
    int row0 = gw * 16;
    if (row0 >= N) return;

    int arow = row0 + (lane & 15);
    if (arow >= N) arow = N - 1;           // duplicate load; rows >= N not stored
    const T* Xp = X + (size_t)arow * DIM + ((lane >> 4) * 8);
    constexpr bool NT = std::is_same<T, float>::value;  // X is single-use stream

    bf16x8 Ah[4], Al[4];
#pragma unroll
    for (int ks = 0; ks < 4; ks++) {
        float v[8];
        load8(Xp + ks * 32, v, NT);
        bf16x8 h, lo;
#pragma unroll
        for (int j = 0; j < 8; j++) {
            short hh = bf16h(v[j]);
            h[j] = hh;
            lo[j] = bf16h(v[j] - bf16f(hh));
        }
        Ah[ks] = h;
        Al[ks] = lo;
    }

    const bf16x8* BH = (const bf16x8*)Bhp;
    const bf16x8* BL = (const bf16x8*)Blp;

    f32x4 acc[8];
#pragma unroll
    for (int nt = 0; nt < 8; nt++) {
        f32x4 c = {0.f, 0.f, 0.f, 0.f};
#pragma unroll
        for (int ks = 0; ks < 4; ks++) {
            bf16x8 bh = BH[(nt * 4 + ks) * 64 + lane];
            bf16x8 bl = BL[(nt * 4 + ks) * 64 + lane];
            c = __builtin_amdgcn_mfma_f32_16x16x32_bf16(Ah[ks], bh, c, 0, 0, 0);
            c = __builtin_amdgcn_mfma_f32_16x16x32_bf16(Al[ks], bh, c, 0, 0, 0);
            c = __builtin_amdgcn_mfma_f32_16x16x32_bf16(Ah[ks], bl, c, 0, 0, 0);
        }
        acc[nt] = c;
    }

    // C/D: col = lane&15 (+nt*16), row = (lane>>4)*4 + reg   [m89/m91]
    int rb = row0 + ((lane >> 4) * 4);
    int cb = lane & 15;
#pragma unroll
    for (int r = 0; r < 4; r++) {
        if (rb + r < N) {
            float dv = dinv[rb + r];
            __half* out = Hh + (size_t)(rb + r) * DIM + cb;
#pragma unroll
            for (int nt = 0; nt < 8; nt++)
                out[nt * 16] = __float2half(acc[nt][r] * dv);
        }
    }
}

// ---------------- aggregation core: one wave per dst node ----------------
__device__ __forceinline__ float2 agg_row(const __half2* __restrict__ Hh,
                                          const int* __restrict__ row_ptr,
                                          const int* __restrict__ col,
                                          const float* __restrict__ dinv,
                                          const float* __restrict__ B,
                                          int wid, int lane) {
    int beg = __builtin_amdgcn_readfirstlane(row_ptr[wid]);
    int end = __builtin_amdgcn_readfirstlane(row_ptr[wid + 1]);
    const __half2* Hl = Hh + lane;  // row s -> Hl[s*64]
    float2 s0f = __half22float2(Hl[(size_t)wid * 64]);  // self (H'[d])
    float ax = s0f.x, ay = s0f.y;
    float bx = 0.f, by = 0.f, cx = 0.f, cy = 0.f, dx = 0.f, dy = 0.f;

    int e = beg;
    for (; e + 16 <= end; e += 16) {
        __half2 g[16];
#pragma unroll
        for (int j = 0; j < 16; j++) g[j] = Hl[(size_t)col[e + j] * 64];
#pragma unroll
        for (int j = 0; j < 16; j += 4) {
            float2 f0 = __half22float2(g[j + 0]);
            float2 f1 = __half22float2(g[j + 1]);
            float2 f2 = __half22float2(g[j + 2]);
            float2 f3 = __half22float2(g[j + 3]);
            ax += f0.x; ay += f0.y;  bx += f1.x; by += f1.y;
            cx += f2.x; cy += f2.y;  dx += f3.x; dy += f3.y;
        }
    }
    for (; e + 8 <= end; e += 8) {
        __half2 g[8];
#pragma unroll
        for (int j = 0; j < 8; j++) g[j] = Hl[(size_t)col[e + j] * 64];
#pragma unroll
        for (int j = 0; j < 8; j += 4) {
            float2 f0 = __half22float2(g[j + 0]);
            float2 f1 = __half22float2(g[j + 1]);
            float2 f2 = __half22float2(g[j + 2]);
            float2 f3 = __half22float2(g[j + 3]);
            ax += f0.x; ay += f0.y;  bx += f1.x; by += f1.y;
            cx += f2.x; cy += f2.y;  dx += f3.x; dy += f3.y;
        }
    }
    for (; e + 4 <= end; e += 4) {
        __half2 g0 = Hl[(size_t)col[e + 0] * 64];
        __half2 g1 = Hl[(size_t)col[e + 1] * 64];
        __half2 g2 = Hl[(size_t)col[e + 2] * 64];
        __half2 g3 = Hl[(size_t)col[e + 3] * 64];
        float2 f0 = __half22float2(g0), f1 = __half22float2(g1);
        float2 f2 = __half22float2(g2), f3 = __half22float2(g3);
        ax += f0.x; ay += f0.y;  bx += f1.x; by += f1.y;
        cx += f2.x; cy += f2.y;  dx += f3.x; dy += f3.y;
    }
    for (; e < end; e++) {
        float2 f = __half22float2(Hl[(size_t)col[e] * 64]);
        ax += f.x; ay += f.y;
    }
    ax += bx + cx + dx;
    ay += by + cy + dy;

    float di = dinv[wid];
    float2 b = *(const float2*)(B + lane * 2);
    return make_float2(fmaf(di, ax, b.x), fmaf(di, ay, b.y));
}

// layer-1: write relu'd fp16 row
__global__ __launch_bounds__(256) void k_agg(const __half2* __restrict__ Hh,
                                             const int* __restrict__ row_ptr,
                                             const int* __restrict__ col,
                                             const float* __restrict__ dinv,
                                             const float* __restrict__ B,
                                             __half2* __restrict__ O, int N) {
    int wid = (blockIdx.x * 256 + threadIdx.x) >> 6;
    int lane = threadIdx.x & 63;
    if (wid >= N) return;
    float2 r = agg_row(Hh, row_ptr, col, dinv, B, wid, lane);
    O[(size_t)wid * 64 + lane] = __floats2half2_rn(fmaxf(r.x, 0.f), fmaxf(r.y, 0.f));
}

// layer-2 + readout fused: out[n] = dot(relu(row), Wr) + br
__global__ __launch_bounds__(256) void k_agg_out(const __half2* __restrict__ Hh,
                                                 const int* __restrict__ row_ptr,
                                                 const int* __restrict__ col,
                                                 const float* __restrict__ dinv,
                                                 const float* __restrict__ B,
                                                 const float* __restrict__ Wr,
                                                 const float* __restrict__ br,
                                                 float* __restrict__ out, int N) {
    int wid = (blockIdx.x * 256 + threadIdx.x) >> 6;
    int lane = threadIdx.x & 63;
    if (wid >= N) return;
    float2 r = agg_row(Hh, row_ptr, col, dinv, B, wid, lane);
    float2 w = *(const float2*)(Wr + lane * 2);
    float v = fmaxf(r.x, 0.f) * w.x + fmaxf(r.y, 0.f) * w.y;
#pragma unroll
    for (int off = 32; off > 0; off >>= 1) v += __shfl_down(v, off, 64);
    if (lane == 0) out[wid] = v + br[0];
}

extern "C" void kernel_launch(void* const* d_in, const int* in_sizes, int n_in,
                              void* d_out, int out_size, void* d_ws, size_t ws_size,
                              hipStream_t stream) {
    const float* x  = (const float*)d_in[0];
    const int*   ei = (const int*)d_in[1];
    const float* W1 = (const float*)d_in[2];
    const float* b1 = (const float*)d_in[3];
    const float* W2 = (const float*)d_in[4];
    const float* b2 = (const float*)d_in[5];
    const float* Wr = (const float*)d_in[6];
    const float* br = (const float*)d_in[7];

    const int N = in_sizes[0] / DIM;
    const int E = in_sizes[1] / 2;
    const int* src = ei;
    const int* dst = ei + E;
    const int NB = (N + 63) >> BSH;  // buckets of 64 nodes

    char* p = (char*)d_ws;
    auto alloc = [&](size_t bytes) -> void* {
        void* r = (void*)p;
        p += (bytes + 255) & ~(size_t)255;
        return r;
    };
    __half*   Hh      = (__half*)alloc((size_t)N * DIM * 2);   // fp16 H'
    __half*   A1      = (__half*)alloc((size_t)N * DIM * 2);   // layer-1 out fp16
    float*    dinv    = (float*)alloc((size_t)N * 4);
    int*      row_ptr = (int*)alloc((size_t)(N + 1) * 4);
    int*      h_part  = (int*)alloc((size_t)HB * 1024 * 4);
    int*      bptr    = (int*)alloc((size_t)(NB + 1) * 4);
    int*      bcur    = (int*)alloc((size_t)NB * 4);
    unsigned* pairs   = (unsigned*)alloc((size_t)E * 4);
    int*      col     = (int*)alloc((size_t)E * 4);
    short*    Bh1     = (short*)alloc(16384 * 2);
    short*    Bl1     = (short*)alloc(16384 * 2);
    short*    Bh2     = (short*)alloc(16384 * 2);
    short*    Bl2     = (short*)alloc(16384 * 2);
    (void)ws_size; (void)n_in;

    // prep: W frags + hist partials
    k_prep<<<HB, 256, 0, stream>>>(W1, W2, Bh1, Bl1, Bh2, Bl2, dst, h_part, E, NB);
    k_bscan<<<1, 1024, 0, stream>>>(h_part, bptr, bcur, NB, E);
    const int binb = (E + 256 * BIN_EPT - 1) / (256 * BIN_EPT);
    k_bin<<<binb, 256, 0, stream>>>(src, dst, bcur, pairs, E, NB);
    k_fill2<<<NB, 256, 0, stream>>>(pairs, bptr, row_ptr, dinv, col, N, NB, E);

    const int mmb = ((N + 15) / 16 + 3) / 4;   // waves of 16 rows, 4 waves/block
    const int ab  = (N * 64 + 255) / 256;

    k_mm<float><<<mmb, 256, 0, stream>>>(x, Bh1, Bl1, dinv, Hh, N);
    k_agg<<<ab, 256, 0, stream>>>((const __half2*)Hh, row_ptr, col, dinv, b1,
                                  (__half2*)A1, N);
    k_mm<__half><<<mmb, 256, 0, stream>>>(A1, Bh2, Bl2, dinv, Hh, N);
    k_agg_out<<<ab, 256, 0, stream>>>((const __half2*)Hh, row_ptr, col, dinv, b2,
                                      Wr, br, (float*)d_out, N);
}

// Round 12
// 131.418 us; speedup vs baseline: 1.0324x; 1.0324x over previous
//
#include <hip/hip_runtime.h>
#include <hip/hip_fp16.h>
#include <cstdint>
#include <cstddef>

// GCN refold: H'_l = dinv * (X_l @ W_l)  (fp16), layer out = relu(dinv*(sum+self)+b)
// GEMM via MFMA bf16 hi/lo split. CSR build: prep(wfrag+hist-partials) ->
// bscan(sum+scan) -> bin(int4 loads, block-local scatter) -> fill2 (LDS-local).
// Requires N < 65536.  [R9 configuration — best measured: 131.5µs]

constexpr int DIM = 128;
#define BSH 6                 // 64 nodes per bucket
#define HB 128                // hist blocks (also wfrag: 128*256 = 32768 threads)
#define BIN_EPT 12            // edges per thread in k_bin (multiple of 4)
#define FT 8                  // src tiles (in-row CSR order; harmless)
#define FSH 13
#define STAGE 2048            // LDS edge stage per bucket

typedef __attribute__((ext_vector_type(8))) short bf16x8;   // 8 bf16 (4 VGPRs)
typedef __attribute__((ext_vector_type(4))) float f32x4;

__device__ __forceinline__ short bf16h(float x) {
    unsigned u = __float_as_uint(x);
    return (short)((u + 0x7FFFu + ((u >> 16) & 1u)) >> 16);  // RNE bf16
}
__device__ __forceinline__ float bf16f(short h) {
    return __uint_as_float(((unsigned)(unsigned short)h) << 16);
}

// ---- prep: W->bf16 hi/lo frags (both layers) + hist partials (no atomics) --
__global__ __launch_bounds__(256) void k_prep(const float* __restrict__ W1,
                                              const float* __restrict__ W2,
                                              short* __restrict__ Bh1,
                                              short* __restrict__ Bl1,
                                              short* __restrict__ Bh2,
                                              short* __restrict__ Bl2,
                                              const int* __restrict__ dst,
                                              int* __restrict__ h_part,
                                              int E, int nb) {
    // part 1: weight fragments (exactly HB*256 = 32768 threads, 2 layers)
    {
        int idx = blockIdx.x * 256 + threadIdx.x;
        const float* W = (idx < 16384) ? W1 : W2;
        short* Bh = (idx < 16384) ? Bh1 : Bh2;
        short* Bl = (idx < 16384) ? Bl1 : Bl2;
        int id = idx & 16383;
        int j  = id & 7;
        int l  = (id >> 3) & 63;
        int ks = (id >> 9) & 3;
        int nt = id >> 11;
        int k  = ks * 32 + ((l >> 4) * 8) + j;
        int c  = nt * 16 + (l & 15);
        float w = W[k * 128 + c];
        short h = bf16h(w);
        Bh[id] = h;
        Bl[id] = bf16h(w - bf16f(h));
    }
    // part 2: bucket histogram partials (LDS, written per block — no atomics)
    __shared__ int h[1024];
    for (int i = threadIdx.x; i < 1024; i += 256) h[i] = 0;
    __syncthreads();
    int E4 = E >> 2;
    for (int v = blockIdx.x * 256 + threadIdx.x; v < E4; v += HB * 256) {
        int4 d4 = *(const int4*)(dst + v * 4);
        atomicAdd(&h[d4.x >> BSH], 1);
        atomicAdd(&h[d4.y >> BSH], 1);
        atomicAdd(&h[d4.z >> BSH], 1);
        atomicAdd(&h[d4.w >> BSH], 1);
    }
    if (blockIdx.x == 0 && threadIdx.x < (E & 3))
        atomicAdd(&h[dst[E4 * 4 + threadIdx.x] >> BSH], 1);
    __syncthreads();
    for (int i = threadIdx.x; i < nb; i += 256)
        h_part[blockIdx.x * 1024 + i] = h[i];
}

// ---- bucket scan: sum HB partials per bucket, exclusive scan ------------
__global__ __launch_bounds__(1024) void k_bscan(const int* __restrict__ h_part,
                                                int* __restrict__ bptr,
                                                int* __restrict__ bcur, int nb, int E) {
    __shared__ int s[1024];
    int t = threadIdx.x;
    int v = 0;
    if (t < nb)
        for (int b = 0; b < HB; b++) v += h_part[b * 1024 + t];
    s[t] = v;
    __syncthreads();
    for (int off = 1; off < 1024; off <<= 1) {
        int u = (t >= off) ? s[t - off] : 0;
        __syncthreads();
        s[t] += u;
        __syncthreads();
    }
    if (t < nb) { int ex = s[t] - v; bptr[t] = ex; bcur[t] = ex; }
    if (t == 0) bptr[nb] = E;
}

// ---- bin edges into bucket runs (block-level reservation, int4 loads) ----
__global__ __launch_bounds__(256) void k_bin(const int* __restrict__ src,
                                             const int* __restrict__ dst,
                                             int* __restrict__ bcur,
                                             unsigned* __restrict__ pairs,
                                             int E, int nb) {
    __shared__ int h[1024];     // local counts
    __shared__ int base[1024];  // reserved cursors
    for (int i = threadIdx.x; i < nb; i += 256) h[i] = 0;
    __syncthreads();

    int e0 = blockIdx.x * 256 * BIN_EPT;
    unsigned u[BIN_EPT];
    int cnt = 0;
#pragma unroll
    for (int j = 0; j < BIN_EPT / 4; j++) {
        int b4 = e0 + j * 1024 + threadIdx.x * 4;
        if (b4 + 4 <= E) {
            int4 s4 = *(const int4*)(src + b4);
            int4 d4 = *(const int4*)(dst + b4);
            u[4 * j + 0] = ((unsigned)d4.x << 16) | (unsigned)s4.x;
            u[4 * j + 1] = ((unsigned)d4.y << 16) | (unsigned)s4.y;
            u[4 * j + 2] = ((unsigned)d4.z << 16) | (unsigned)s4.z;
            u[4 * j + 3] = ((unsigned)d4.w << 16) | (unsigned)s4.w;
            atomicAdd(&h[d4.x >> BSH], 1);
            atomicAdd(&h[d4.y >> BSH], 1);
            atomicAdd(&h[d4.z >> BSH], 1);
            atomicAdd(&h[d4.w >> BSH], 1);
            cnt = 4 * j + 4;
        } else {
#pragma unroll
            for (int k = 0; k < 4; k++) {
                int e = b4 + k;
                if (e < E) {
                    int d = dst[e];
                    u[4 * j + k] = ((unsigned)d << 16) | (unsigned)src[e];
                    atomicAdd(&h[d >> BSH], 1);
                    cnt = 4 * j + k + 1;
                }
            }
        }
    }
    __syncthreads();
    for (int i = threadIdx.x; i < nb; i += 256) {
        int c = h[i];
        base[i] = c ? atomicAdd(&bcur[i], c) : 0;
    }
    __syncthreads();
#pragma unroll
    for (int j = 0; j < BIN_EPT; j++) {
        if (j < cnt) {
            int pos = atomicAdd(&base[u[j] >> 22], 1);
            pairs[pos] = u[j];
        }
    }
}

// ---- per-bucket: row_ptr, dinv, CSR col fill in src-tile order ----------
__global__ __launch_bounds__(256) void k_fill2(const unsigned* __restrict__ pairs,
                                               const int* __restrict__ bptr,
                                               int* __restrict__ row_ptr,
                                               float* __restrict__ dinv,
                                               int* __restrict__ col,
                                               int N, int nb, int E) {
    __shared__ unsigned sp[STAGE];
    __shared__ int lcnt[64 * FT];   // counts, then running cursors
    int b = blockIdx.x;
    int node0 = b << BSH;
    int beg = bptr[b], end = bptr[b + 1];
    int cnt = end - beg;
    bool useStage = (cnt <= STAGE);

    for (int i = threadIdx.x; i < 64 * FT; i += 256) lcnt[i] = 0;
    __syncthreads();

    // pass A: (stage +) count per (node, src-tile)
    for (int i = threadIdx.x; i < cnt; i += 256) {
        unsigned u = pairs[beg + i];
        if (useStage) sp[i] = u;
        atomicAdd(&lcnt[((u >> 16) & 63) * FT + ((u & 0xffffu) >> FSH)], 1);
    }
    __syncthreads();

    // wave 0: per-node totals, wave-scan, write row_ptr/dinv, tile cursors
    if (threadIdx.x < 64) {
        int t = threadIdx.x;
        int c[FT]; int sum = 0;
#pragma unroll
        for (int f = 0; f < FT; f++) { c[f] = lcnt[t * FT + f]; sum += c[f]; }
        int x = sum;
#pragma unroll
        for (int off = 1; off < 64; off <<= 1) {
            int y = __shfl_up(x, off, 64);
            if (t >= off) x += y;
        }
        int nodebase = beg + x - sum;   // exclusive in-bucket prefix
        int node = node0 + t;
        if (node < N) {
            row_ptr[node] = nodebase;
            dinv[node] = rsqrtf((float)sum + 1.0f);
        }
        int run = nodebase;
#pragma unroll
        for (int f = 0; f < FT; f++) { lcnt[t * FT + f] = run; run += c[f]; }
        if (b == nb - 1 && t == 0) row_ptr[N] = E;
    }
    __syncthreads();

    // pass B: place
    for (int i = threadIdx.x; i < cnt; i += 256) {
        unsigned u = useStage ? sp[i] : pairs[beg + i];
        unsigned s = u & 0xffffu;
        int pos = atomicAdd(&lcnt[((u >> 16) & 63) * FT + (s >> FSH)], 1);
        col[pos] = (int)s;
    }
}

// ---------------- MFMA GEMM: H' = dinv * (X @ W), fp16 out --------------
__device__ __forceinline__ void load8(const float* p, float* v) {
    float4 a = *(const float4*)p;
    float4 b = *(const float4*)(p + 4);
    v[0] = a.x; v[1] = a.y; v[2] = a.z; v[3] = a.w;
    v[4] = b.x; v[5] = b.y; v[6] = b.z; v[7] = b.w;
}
__device__ __forceinline__ void load8(const __half* p, float* v) {
    float4 a = *(const float4*)p;   // 8 halves
    const __half2* h = (const __half2*)&a;
#pragma unroll
    for (int i = 0; i < 4; i++) {
        float2 f = __half22float2(h[i]);
        v[2 * i] = f.x; v[2 * i + 1] = f.y;
    }
}

template <typename T>
__global__ __launch_bounds__(256) void k_mm(const T* __restrict__ X,
                                            const short* __restrict__ Bhp,
                                            const short* __restrict__ Blp,
                                            const float* __restrict__ dinv,
                                            __half* __restrict__ Hh, int N) {
    int gw   = (blockIdx.x * 256 + threadIdx.x) >> 6;
    int lane = threadIdx.x & 63;
    int row0 = gw * 16;
    if (row0 >= N) return;

    int arow = row0 + (lane & 15);
    if (arow >= N) arow = N - 1;           // duplicate load; rows >= N not stored
    const T* Xp = X + (size_t)arow * DIM + ((lane >> 4) * 8);

    bf16x8 Ah[4], Al[4];
#pragma unroll
    for (int ks = 0; ks < 4; ks++) {
        float v[8];
        load8(Xp + ks * 32, v);
        bf16x8 h, lo;
#pragma unroll
        for (int j = 0; j < 8; j++) {
            short hh = bf16h(v[j]);
            h[j] = hh;
            lo[j] = bf16h(v[j] - bf16f(hh));
        }
        Ah[ks] = h;
        Al[ks] = lo;
    }

    const bf16x8* BH = (const bf16x8*)Bhp;
    const bf16x8* BL = (const bf16x8*)Blp;

    f32x4 acc[8];
#pragma unroll
    for (int nt = 0; nt < 8; nt++) {
        f32x4 c = {0.f, 0.f, 0.f, 0.f};
#pragma unroll
        for (int ks = 0; ks < 4; ks++) {
            bf16x8 bh = BH[(nt * 4 + ks) * 64 + lane];
            bf16x8 bl = BL[(nt * 4 + ks) * 64 + lane];
            c = __builtin_amdgcn_mfma_f32_16x16x32_bf16(Ah[ks], bh, c, 0, 0, 0);
            c = __builtin_amdgcn_mfma_f32_16x16x32_bf16(Al[ks], bh, c, 0, 0, 0);
            c = __builtin_amdgcn_mfma_f32_16x16x32_bf16(Ah[ks], bl, c, 0, 0, 0);
        }
        acc[nt] = c;
    }

    // C/D: col = lane&15 (+nt*16), row = (lane>>4)*4 + reg   [m89/m91]
    int rb = row0 + ((lane >> 4) * 4);
    int cb = lane & 15;
#pragma unroll
    for (int r = 0; r < 4; r++) {
        if (rb + r < N) {
            float dv = dinv[rb + r];
            __half* out = Hh + (size_t)(rb + r) * DIM + cb;
#pragma unroll
            for (int nt = 0; nt < 8; nt++)
                out[nt * 16] = __float2half(acc[nt][r] * dv);
        }
    }
}

// ---------------- aggregation core: one wave per dst node ----------------
__device__ __forceinline__ float2 agg_row(const __half2* __restrict__ Hh,
                                          const int* __restrict__ row_ptr,
                                          const int* __restrict__ col,
                                          const float* __restrict__ dinv,
                                          const float* __restrict__ B,
                                          int wid, int lane) {
    int beg = __builtin_amdgcn_readfirstlane(row_ptr[wid]);
    int end = __builtin_amdgcn_readfirstlane(row_ptr[wid + 1]);
    const __half2* Hl = Hh + lane;  // row s -> Hl[s*64]
    float2 s0f = __half22float2(Hl[(size_t)wid * 64]);  // self (H'[d])
    float ax = s0f.x, ay = s0f.y;
    float bx = 0.f, by = 0.f, cx = 0.f, cy = 0.f, dx = 0.f, dy = 0.f;

    int e = beg;
    for (; e + 16 <= end; e += 16) {
        __half2 g[16];
#pragma unroll
        for (int j = 0; j < 16; j++) g[j] = Hl[(size_t)col[e + j] * 64];
#pragma unroll
        for (int j = 0; j < 16; j += 4) {
            float2 f0 = __half22float2(g[j + 0]);
            float2 f1 = __half22float2(g[j + 1]);
            float2 f2 = __half22float2(g[j + 2]);
            float2 f3 = __half22float2(g[j + 3]);
            ax += f0.x; ay += f0.y;  bx += f1.x; by += f1.y;
            cx += f2.x; cy += f2.y;  dx += f3.x; dy += f3.y;
        }
    }
    for (; e + 8 <= end; e += 8) {
        __half2 g[8];
#pragma unroll
        for (int j = 0; j < 8; j++) g[j] = Hl[(size_t)col[e + j] * 64];
#pragma unroll
        for (int j = 0; j < 8; j += 4) {
            float2 f0 = __half22float2(g[j + 0]);
            float2 f1 = __half22float2(g[j + 1]);
            float2 f2 = __half22float2(g[j + 2]);
            float2 f3 = __half22float2(g[j + 3]);
            ax += f0.x; ay += f0.y;  bx += f1.x; by += f1.y;
            cx += f2.x; cy += f2.y;  dx += f3.x; dy += f3.y;
        }
    }
    for (; e + 4 <= end; e += 4) {
        __half2 g0 = Hl[(size_t)col[e + 0] * 64];
        __half2 g1 = Hl[(size_t)col[e + 1] * 64];
        __half2 g2 = Hl[(size_t)col[e + 2] * 64];
        __half2 g3 = Hl[(size_t)col[e + 3] * 64];
        float2 f0 = __half22float2(g0), f1 = __half22float2(g1);
        float2 f2 = __half22float2(g2), f3 = __half22float2(g3);
        ax += f0.x; ay += f0.y;  bx += f1.x; by += f1.y;
        cx += f2.x; cy += f2.y;  dx += f3.x; dy += f3.y;
    }
    for (; e < end; e++) {
        float2 f = __half22float2(Hl[(size_t)col[e] * 64]);
        ax += f.x; ay += f.y;
    }
    ax += bx + cx + dx;
    ay += by + cy + dy;

    float di = dinv[wid];
    float2 b = *(const float2*)(B + lane * 2);
    return make_float2(fmaf(di, ax, b.x), fmaf(di, ay, b.y));
}

// layer-1: write relu'd fp16 row
__global__ __launch_bounds__(256) void k_agg(const __half2* __restrict__ Hh,
                                             const int* __restrict__ row_ptr,
                                             const int* __restrict__ col,
                                             const float* __restrict__ dinv,
                                             const float* __restrict__ B,
                                             __half2* __restrict__ O, int N) {
    int wid = (blockIdx.x * 256 + threadIdx.x) >> 6;
    int lane = threadIdx.x & 63;
    if (wid >= N) return;
    float2 r = agg_row(Hh, row_ptr, col, dinv, B, wid, lane);
    O[(size_t)wid * 64 + lane] = __floats2half2_rn(fmaxf(r.x, 0.f), fmaxf(r.y, 0.f));
}

// layer-2 + readout fused: out[n] = dot(relu(row), Wr) + br
__global__ __launch_bounds__(256) void k_agg_out(const __half2* __restrict__ Hh,
                                                 const int* __restrict__ row_ptr,
                                                 const int* __restrict__ col,
                                                 const float* __restrict__ dinv,
                                                 const float* __restrict__ B,
                                                 const float* __restrict__ Wr,
                                                 const float* __restrict__ br,
                                                 float* __restrict__ out, int N) {
    int wid = (blockIdx.x * 256 + threadIdx.x) >> 6;
    int lane = threadIdx.x & 63;
    if (wid >= N) return;
    float2 r = agg_row(Hh, row_ptr, col, dinv, B, wid, lane);
    float2 w = *(const float2*)(Wr + lane * 2);
    float v = fmaxf(r.x, 0.f) * w.x + fmaxf(r.y, 0.f) * w.y;
#pragma unroll
    for (int off = 32; off > 0; off >>= 1) v += __shfl_down(v, off, 64);
    if (lane == 0) out[wid] = v + br[0];
}

extern "C" void kernel_launch(void* const* d_in, const int* in_sizes, int n_in,
                              void* d_out, int out_size, void* d_ws, size_t ws_size,
                              hipStream_t stream) {
    const float* x  = (const float*)d_in[0];
    const int*   ei = (const int*)d_in[1];
    const float* W1 = (const float*)d_in[2];
    const float* b1 = (const float*)d_in[3];
    const float* W2 = (const float*)d_in[4];
    const float* b2 = (const float*)d_in[5];
    const float* Wr = (const float*)d_in[6];
    const float* br = (const float*)d_in[7];

    const int N = in_sizes[0] / DIM;
    const int E = in_sizes[1] / 2;
    const int* src = ei;
    const int* dst = ei + E;
    const int NB = (N + 63) >> BSH;  // buckets of 64 nodes

    char* p = (char*)d_ws;
    auto alloc = [&](size_t bytes) -> void* {
        void* r = (void*)p;
        p += (bytes + 255) & ~(size_t)255;
        return r;
    };
    __half*   Hh      = (__half*)alloc((size_t)N * DIM * 2);   // fp16 H'
    __half*   A1      = (__half*)alloc((size_t)N * DIM * 2);   // layer-1 out fp16
    float*    dinv    = (float*)alloc((size_t)N * 4);
    int*      row_ptr = (int*)alloc((size_t)(N + 1) * 4);
    int*      h_part  = (int*)alloc((size_t)HB * 1024 * 4);
    int*      bptr    = (int*)alloc((size_t)(NB + 1) * 4);
    int*      bcur    = (int*)alloc((size_t)NB * 4);
    unsigned* pairs   = (unsigned*)alloc((size_t)E * 4);
    int*      col     = (int*)alloc((size_t)E * 4);
    short*    Bh1     = (short*)alloc(16384 * 2);
    short*    Bl1     = (short*)alloc(16384 * 2);
    short*    Bh2     = (short*)alloc(16384 * 2);
    short*    Bl2     = (short*)alloc(16384 * 2);
    (void)ws_size; (void)n_in;

    // prep: W frags + hist partials
    k_prep<<<HB, 256, 0, stream>>>(W1, W2, Bh1, Bl1, Bh2, Bl2, dst, h_part, E, NB);
    k_bscan<<<1, 1024, 0, stream>>>(h_part, bptr, bcur, NB, E);
    const int binb = (E + 256 * BIN_EPT - 1) / (256 * BIN_EPT);
    k_bin<<<binb, 256, 0, stream>>>(src, dst, bcur, pairs, E, NB);
    k_fill2<<<NB, 256, 0, stream>>>(pairs, bptr, row_ptr, dinv, col, N, NB, E);

    const int mmb = ((N + 15) / 16 + 3) / 4;   // waves of 16 rows, 4 waves/block
    const int ab  = (N * 64 + 255) / 256;

    k_mm<float><<<mmb, 256, 0, stream>>>(x, Bh1, Bl1, dinv, Hh, N);
    k_agg<<<ab, 256, 0, stream>>>((const __half2*)Hh, row_ptr, col, dinv, b1,
                                  (__half2*)A1, N);
    k_mm<__half><<<mmb, 256, 0, stream>>>(A1, Bh2, Bl2, dinv, Hh, N);
    k_agg_out<<<ab, 256, 0, stream>>>((const __half2*)Hh, row_ptr, col, dinv, b2,
                                      Wr, br, (float*)d_out, N);
}